// Round 1
// baseline (1736.217 us; speedup 1.0000x reference)
//
#include <hip/hip_runtime.h>

// ---------------------------------------------------------------------------
// DTFDynamicLayer: router top-k gather -> Qwen2 block (bf16 MFMA GEMMs,
// fp32 flash attention) -> gated scatter.  B=2,T=2048,D=2048,H=16,HD=128,
// I=5632, K=1024, S=2048.  All fixed at compile time.
// ---------------------------------------------------------------------------

typedef unsigned short u16;
typedef unsigned int u32;
typedef short bf16x8 __attribute__((ext_vector_type(8)));
typedef float f32x4 __attribute__((ext_vector_type(4)));

#define T_LEN 2048
#define D_DIM 2048
#define B_DIM 2
#define H_NUM 16
#define HD_DIM 128
#define I_DIM 5632
#define K_CAP 1024
#define S_TOT 2048

__device__ __forceinline__ u16 f2bf(float f) {
  union { float f; u32 u; } a; a.f = f;
  u32 r = a.u + 0x7fffu + ((a.u >> 16) & 1u);
  return (u16)(r >> 16);
}

__device__ __forceinline__ void cvt8(const u16* p, float* f) {
  const uint4 u = *(const uint4*)p;
  f[0] = __uint_as_float(u.x << 16);
  f[1] = __uint_as_float(u.x & 0xffff0000u);
  f[2] = __uint_as_float(u.y << 16);
  f[3] = __uint_as_float(u.y & 0xffff0000u);
  f[4] = __uint_as_float(u.z << 16);
  f[5] = __uint_as_float(u.z & 0xffff0000u);
  f[6] = __uint_as_float(u.w << 16);
  f[7] = __uint_as_float(u.w & 0xffff0000u);
}

__device__ __forceinline__ void gld_lds16(const void* g, void* l) {
  void* gg = const_cast<void*>(g);
  __builtin_amdgcn_global_load_lds(
      (__attribute__((address_space(1))) u32*)gg,
      (__attribute__((address_space(3))) u32*)l, 16, 0, 0);
}

// ---------------- router: scores[b,t] = bcu*||o-p|| + bce*(||p-pr||+off) ----
__global__ __launch_bounds__(256)
void router_kernel(const float* __restrict__ orig, const float* __restrict__ post,
                   const float* __restrict__ prior, const float* __restrict__ bce,
                   const float* __restrict__ bcu, const float* __restrict__ coff,
                   float* __restrict__ scores) {
  const int row = blockIdx.x;
  const size_t base = (size_t)row * D_DIM;
  float s1 = 0.f, s2 = 0.f;
  for (int d = threadIdx.x * 4; d < D_DIM; d += 1024) {
    float4 o = *(const float4*)(orig + base + d);
    float4 p = *(const float4*)(post + base + d);
    float4 r = *(const float4*)(prior + base + d);
    float a;
    a = o.x - p.x; s1 += a * a;  a = o.y - p.y; s1 += a * a;
    a = o.z - p.z; s1 += a * a;  a = o.w - p.w; s1 += a * a;
    a = p.x - r.x; s2 += a * a;  a = p.y - r.y; s2 += a * a;
    a = p.z - r.z; s2 += a * a;  a = p.w - r.w; s2 += a * a;
  }
#pragma unroll
  for (int k = 32; k; k >>= 1) { s1 += __shfl_down(s1, k); s2 += __shfl_down(s2, k); }
  __shared__ float r1[4], r2[4];
  const int wv = threadIdx.x >> 6;
  if ((threadIdx.x & 63) == 0) { r1[wv] = s1; r2[wv] = s2; }
  __syncthreads();
  if (threadIdx.x == 0) {
    float cu = sqrtf(r1[0] + r1[1] + r1[2] + r1[3]);
    float ce = sqrtf(r2[0] + r2[1] + r2[2] + r2[3]);
    scores[row] = bcu[0] * cu + bce[0] * (ce + coff[0]);
  }
}

// ---------------- rank: stable top-k rank (matches lax.top_k tie-break) -----
__global__ __launch_bounds__(256)
void rank_kernel(const float* __restrict__ scores, int* __restrict__ rnk) {
  const int b = blockIdx.y;
  const int t = blockIdx.x * 256 + threadIdx.x;
  __shared__ float s[T_LEN];
  for (int u = threadIdx.x; u < T_LEN; u += 256) s[u] = scores[b * T_LEN + u];
  __syncthreads();
  const float st = s[t];
  int r = 0;
  for (int u = 0; u < T_LEN; ++u) {
    float su = s[u];
    r += ((su > st) || (su == st && u < t)) ? 1 : 0;
  }
  rnk[b * T_LEN + t] = r;
}

// ---------------- compact: selected (rank<K) in temporal order --------------
__global__ __launch_bounds__(256)
void compact_kernel(const float* __restrict__ scores, const int* __restrict__ rnk,
                    int* __restrict__ tidx, float* __restrict__ gate) {
  const int b = blockIdx.x;
  const int base = b * T_LEN;
  __shared__ int csum[256];
  int f[8]; int loc = 0;
  const int t0 = threadIdx.x * 8;
#pragma unroll
  for (int i = 0; i < 8; ++i) { f[i] = (rnk[base + t0 + i] < K_CAP) ? 1 : 0; loc += f[i]; }
  csum[threadIdx.x] = loc;
  __syncthreads();
  if (threadIdx.x == 0) {
    int run = 0;
    for (int i = 0; i < 256; ++i) { int tmp = csum[i]; csum[i] = run; run += tmp; }
  }
  __syncthreads();
  int pos = csum[threadIdx.x];
#pragma unroll
  for (int i = 0; i < 8; ++i) {
    if (f[i]) {
      float sc = scores[base + t0 + i];
      tidx[b * K_CAP + pos] = t0 + i;
      gate[b * K_CAP + pos] = 1.f / (1.f + __expf(-sc));
      ++pos;
    }
  }
}

// ---------------- weight transpose + bf16 convert: Wt[n][k] = W[k][n] -------
__global__ __launch_bounds__(256)
void transpose_bf16_kernel(const float* __restrict__ W, u16* __restrict__ Wt,
                           int K, int N) {
  __shared__ float tile[32][33];
  const int bn = blockIdx.x * 32, bk = blockIdx.y * 32;
  const int tx = threadIdx.x & 31, ty = threadIdx.x >> 5;
#pragma unroll
  for (int i = 0; i < 32; i += 8)
    tile[ty + i][tx] = W[(size_t)(bk + ty + i) * N + bn + tx];
  __syncthreads();
#pragma unroll
  for (int i = 0; i < 32; i += 8)
    Wt[(size_t)(bn + ty + i) * K + bk + tx] = f2bf(tile[tx][ty + i]);
}

// ---------------- rmsnorm (optional gather, optional f32 copy, bf16 out) ----
__global__ __launch_bounds__(256)
void rmsnorm_kernel(const float* __restrict__ X, const int* __restrict__ tidx,
                    const float* __restrict__ w, float* __restrict__ xcopy,
                    u16* __restrict__ Y) {
  const int s = blockIdx.x;
  const float* row;
  if (tidx) {
    const int b = s >> 10;
    const int t = tidx[s];
    row = X + ((size_t)b * T_LEN + t) * D_DIM;
  } else {
    row = X + (size_t)s * D_DIM;
  }
  const int d0 = threadIdx.x * 4;
  float4 v0 = *(const float4*)(row + d0);
  float4 v1 = *(const float4*)(row + d0 + 1024);
  float ss = v0.x*v0.x + v0.y*v0.y + v0.z*v0.z + v0.w*v0.w
           + v1.x*v1.x + v1.y*v1.y + v1.z*v1.z + v1.w*v1.w;
#pragma unroll
  for (int k = 32; k; k >>= 1) ss += __shfl_down(ss, k);
  __shared__ float red[4];
  if ((threadIdx.x & 63) == 0) red[threadIdx.x >> 6] = ss;
  __syncthreads();
  const float tot = red[0] + red[1] + red[2] + red[3];
  const float rms = rsqrtf(tot * (1.0f / D_DIM) + 1e-6f);
  if (xcopy) {
    *(float4*)(xcopy + (size_t)s * D_DIM + d0) = v0;
    *(float4*)(xcopy + (size_t)s * D_DIM + d0 + 1024) = v1;
  }
  const float4 w0 = *(const float4*)(w + d0);
  const float4 w1 = *(const float4*)(w + d0 + 1024);
  u16* yp = Y + (size_t)s * D_DIM;
  u32 a0 = (u32)f2bf(v0.x * rms * w0.x) | ((u32)f2bf(v0.y * rms * w0.y) << 16);
  u32 a1 = (u32)f2bf(v0.z * rms * w0.z) | ((u32)f2bf(v0.w * rms * w0.w) << 16);
  *(uint2*)(yp + d0) = make_uint2(a0, a1);
  u32 b0 = (u32)f2bf(v1.x * rms * w1.x) | ((u32)f2bf(v1.y * rms * w1.y) << 16);
  u32 b1 = (u32)f2bf(v1.z * rms * w1.z) | ((u32)f2bf(v1.w * rms * w1.w) << 16);
  *(uint2*)(yp + d0 + 1024) = make_uint2(b0, b1);
}

// ---------------- bf16 MFMA GEMM, m97 structure -----------------------------
// C[M,N] (f32) = A[M,K](bf16) x Bt[N,K](bf16)^T (+bias[col]) (+resid[M,N])
// 128x128 tile, BK=32, 4 waves (2x2), each wave 64x64 via 4x4 of 16x16x32.
__global__ __launch_bounds__(256)
void gemm_bf16_kernel(const u16* __restrict__ A, const u16* __restrict__ Bt,
                      float* __restrict__ C, const float* __restrict__ bias,
                      const float* __restrict__ resid, int M, int N, int K) {
  __shared__ u16 As[128 * 32];
  __shared__ u16 Bs[128 * 32];
  const int tid = threadIdx.x;
  const int w = tid >> 6, l = tid & 63;
  const int row0 = blockIdx.y * 128, col0 = blockIdx.x * 128;
  const int wr = (w >> 1) * 64, wc = (w & 1) * 64;
  const int am = l & 15, ak = (l >> 4) * 8;
  const int srow = l >> 2, scol = (l & 3) * 8;
  (void)M;

  f32x4 acc[4][4] = {};

  const u16* Abase = A + (size_t)(row0 + srow) * K + scol;
  const u16* Bbase = Bt + (size_t)(col0 + srow) * K + scol;
  const int R0 = (w * 2) * 16, R1 = (w * 2 + 1) * 16;

  for (int k0 = 0; k0 < K; k0 += 32) {
    gld_lds16(Abase + (size_t)R0 * K + k0, &As[R0 * 32]);
    gld_lds16(Abase + (size_t)R1 * K + k0, &As[R1 * 32]);
    gld_lds16(Bbase + (size_t)R0 * K + k0, &Bs[R0 * 32]);
    gld_lds16(Bbase + (size_t)R1 * K + k0, &Bs[R1 * 32]);
    __syncthreads();
    bf16x8 af[4], bfr[4];
#pragma unroll
    for (int i = 0; i < 4; ++i) af[i] = *(const bf16x8*)&As[(wr + i * 16 + am) * 32 + ak];
#pragma unroll
    for (int j = 0; j < 4; ++j) bfr[j] = *(const bf16x8*)&Bs[(wc + j * 16 + am) * 32 + ak];
#pragma unroll
    for (int i = 0; i < 4; ++i)
#pragma unroll
      for (int j = 0; j < 4; ++j)
        acc[i][j] = __builtin_amdgcn_mfma_f32_16x16x32_bf16(af[i], bfr[j], acc[i][j], 0, 0, 0);
    __syncthreads();
  }

  const int rb = wr + (l >> 4) * 4;
  const int cb = wc + (l & 15);
#pragma unroll
  for (int i = 0; i < 4; ++i) {
#pragma unroll
    for (int j = 0; j < 4; ++j) {
      const int colg = col0 + cb + j * 16;
      const float bv = bias ? bias[colg] : 0.0f;
#pragma unroll
      for (int r = 0; r < 4; ++r) {
        const int rowg = row0 + rb + i * 16 + r;
        const size_t idx = (size_t)rowg * N + colg;
        float v = acc[i][j][r] + bv;
        if (resid) v += resid[idx];
        C[idx] = v;
      }
    }
  }
}

// ---------------- RoPE in place on q_lin/k_lin [S, H*HD] --------------------
__global__ __launch_bounds__(256)
void rope_kernel(float* __restrict__ q, float* __restrict__ k,
                 const float* __restrict__ cosb, const float* __restrict__ sinb,
                 const int* __restrict__ tidx) {
  const int idx = blockIdx.x * 256 + threadIdx.x;  // < S*H*64
  const int d = idx & 63;
  const int h = (idx >> 6) & 15;
  const int s = idx >> 10;
  const int b = s >> 10;
  const int t = tidx[s];
  const size_t base = (size_t)s * 2048 + h * 128 + d;
  const size_t cb = ((size_t)b * T_LEN + t) * HD_DIM + d;
  const float c1 = cosb[cb], sn1 = sinb[cb];
  const float c2 = cosb[cb + 64], sn2 = sinb[cb + 64];
  float x1v, x2v;
  x1v = q[base]; x2v = q[base + 64];
  q[base] = x1v * c1 - x2v * sn1;
  q[base + 64] = x2v * c2 + x1v * sn2;
  x1v = k[base]; x2v = k[base + 64];
  k[base] = x1v * c1 - x2v * sn1;
  k[base + 64] = x2v * c2 + x1v * sn2;
}

// ---------------- flash attention (fp32 compute, bf16 LDS tiles) ------------
// grid (S/64, H); block 256.  Q tile 64, KV tile 64, online softmax.
__global__ __launch_bounds__(256)
void attn_kernel(const float* __restrict__ Qg, const float* __restrict__ Kg,
                 const float* __restrict__ Vg, u16* __restrict__ Og) {
  const int qt = blockIdx.x;
  const int h = blockIdx.y;
  const int q0 = qt * 64;
  const int tid = threadIdx.x;

  __shared__ u16 Qs[64 * 136];
  __shared__ u16 KVs[64 * 136];
  __shared__ float Ss[64 * 65];
  __shared__ float alpha_s[64];
  __shared__ float linv_s[64];

  for (int i = tid; i < 64 * 32; i += 256) {
    const int r = i >> 5, c4 = i & 31;
    const float4 v = *(const float4*)(Qg + (size_t)(q0 + r) * 2048 + h * 128 + c4 * 4);
    u32 lo = (u32)f2bf(v.x) | ((u32)f2bf(v.y) << 16);
    u32 hi = (u32)f2bf(v.z) | ((u32)f2bf(v.w) << 16);
    *(uint2*)&Qs[r * 136 + c4 * 4] = make_uint2(lo, hi);
  }

  float oacc[4][8];
#pragma unroll
  for (int i = 0; i < 4; ++i)
#pragma unroll
    for (int d = 0; d < 8; ++d) oacc[i][d] = 0.f;

  float m_run = -1e30f, l_run = 0.f;

  const int qb = (tid & 15) * 4;
  const int kb = (tid >> 4) * 4;
  const int d8 = (tid >> 4) * 8;

  const int ntiles = qt + 1;
  for (int kt = 0; kt < ntiles; ++kt) {
    const int kv0 = kt * 64;
    __syncthreads();
    for (int i = tid; i < 64 * 32; i += 256) {
      const int r = i >> 5, c4 = i & 31;
      const float4 v = *(const float4*)(Kg + (size_t)(kv0 + r) * 2048 + h * 128 + c4 * 4);
      u32 lo = (u32)f2bf(v.x) | ((u32)f2bf(v.y) << 16);
      u32 hi = (u32)f2bf(v.z) | ((u32)f2bf(v.w) << 16);
      *(uint2*)&KVs[r * 136 + c4 * 4] = make_uint2(lo, hi);
    }
    __syncthreads();
    {
      float sacc[4][4];
#pragma unroll
      for (int i = 0; i < 4; ++i)
#pragma unroll
        for (int j = 0; j < 4; ++j) sacc[i][j] = 0.f;
      for (int dd = 0; dd < 16; ++dd) {
        float qv[4][8], kv[4][8];
#pragma unroll
        for (int i = 0; i < 4; ++i) cvt8(&Qs[(qb + i) * 136 + dd * 8], qv[i]);
#pragma unroll
        for (int j = 0; j < 4; ++j) cvt8(&KVs[(kb + j) * 136 + dd * 8], kv[j]);
#pragma unroll
        for (int i = 0; i < 4; ++i)
#pragma unroll
          for (int j = 0; j < 4; ++j) {
            float a = 0.f;
#pragma unroll
            for (int d = 0; d < 8; ++d) a += qv[i][d] * kv[j][d];
            sacc[i][j] += a;
          }
      }
      const float scale = 0.088388347648318447f;  // 1/sqrt(128)
#pragma unroll
      for (int i = 0; i < 4; ++i)
#pragma unroll
        for (int j = 0; j < 4; ++j) {
          float sv = sacc[i][j] * scale;
          if (kv0 + kb + j > q0 + qb + i) sv = -1e30f;  // causal
          Ss[(qb + i) * 65 + kb + j] = sv;
        }
    }
    __syncthreads();
    if (tid < 64) {
      const int q = tid;
      float mx = -1e30f;
      for (int j = 0; j < 64; ++j) mx = fmaxf(mx, Ss[q * 65 + j]);
      const float m_new = fmaxf(m_run, mx);
      const float a = __expf(m_run - m_new);
      float sum = 0.f;
      for (int j = 0; j < 64; ++j) {
        const float pexp = __expf(Ss[q * 65 + j] - m_new);
        Ss[q * 65 + j] = pexp;
        sum += pexp;
      }
      l_run = l_run * a + sum;
      m_run = m_new;
      alpha_s[q] = a;
    }
    __syncthreads();
    // stage V over K tile
    for (int i = tid; i < 64 * 32; i += 256) {
      const int r = i >> 5, c4 = i & 31;
      const float4 v = *(const float4*)(Vg + (size_t)(kv0 + r) * 2048 + h * 128 + c4 * 4);
      u32 lo = (u32)f2bf(v.x) | ((u32)f2bf(v.y) << 16);
      u32 hi = (u32)f2bf(v.z) | ((u32)f2bf(v.w) << 16);
      *(uint2*)&KVs[r * 136 + c4 * 4] = make_uint2(lo, hi);
    }
    __syncthreads();
    {
      float al[4];
#pragma unroll
      for (int i = 0; i < 4; ++i) {
        al[i] = alpha_s[qb + i];
#pragma unroll
        for (int d = 0; d < 8; ++d) oacc[i][d] *= al[i];
      }
      for (int j = 0; j < 64; ++j) {
        float vv[8];
        cvt8(&KVs[j * 136 + d8], vv);
        const float p0 = Ss[(qb + 0) * 65 + j];
        const float p1 = Ss[(qb + 1) * 65 + j];
        const float p2 = Ss[(qb + 2) * 65 + j];
        const float p3 = Ss[(qb + 3) * 65 + j];
#pragma unroll
        for (int d = 0; d < 8; ++d) {
          oacc[0][d] += p0 * vv[d];
          oacc[1][d] += p1 * vv[d];
          oacc[2][d] += p2 * vv[d];
          oacc[3][d] += p3 * vv[d];
        }
      }
    }
  }
  if (tid < 64) linv_s[tid] = 1.f / l_run;
  __syncthreads();
#pragma unroll
  for (int i = 0; i < 4; ++i) {
    const float li = linv_s[qb + i];
    u32 pk[4];
#pragma unroll
    for (int dd = 0; dd < 4; ++dd)
      pk[dd] = (u32)f2bf(oacc[i][dd * 2] * li) | ((u32)f2bf(oacc[i][dd * 2 + 1] * li) << 16);
    *(uint4*)(Og + (size_t)(q0 + qb + i) * 2048 + h * 128 + d8) = make_uint4(pk[0], pk[1], pk[2], pk[3]);
  }
}

// ---------------- silu(gate)*up -> bf16 -------------------------------------
__global__ __launch_bounds__(256)
void silu_mul_kernel(const float* __restrict__ g, const float* __restrict__ u,
                     u16* __restrict__ out) {
  const size_t i = ((size_t)blockIdx.x * 256 + threadIdx.x) * 4;
  float4 gv = *(const float4*)(g + i);
  float4 uv = *(const float4*)(u + i);
  float r0 = gv.x * uv.x / (1.f + __expf(-gv.x));
  float r1 = gv.y * uv.y / (1.f + __expf(-gv.y));
  float r2 = gv.z * uv.z / (1.f + __expf(-gv.z));
  float r3 = gv.w * uv.w / (1.f + __expf(-gv.w));
  u32 a0 = (u32)f2bf(r0) | ((u32)f2bf(r1) << 16);
  u32 a1 = (u32)f2bf(r2) | ((u32)f2bf(r3) << 16);
  *(uint2*)(out + i) = make_uint2(a0, a1);
}

// ---------------- gated scatter back ----------------------------------------
__global__ __launch_bounds__(256)
void scatter_kernel(const float* __restrict__ hs, const float* __restrict__ x2,
                    const int* __restrict__ tidx, const float* __restrict__ gate,
                    float* __restrict__ out) {
  const int s = blockIdx.x;
  const int b = s >> 10;
  const int t = tidx[s];
  const float gg = gate[s];
  const size_t src = (size_t)s * D_DIM;
  const size_t dst = ((size_t)b * T_LEN + t) * D_DIM;
  for (int d = threadIdx.x * 4; d < D_DIM; d += 1024) {
    float4 hv = *(const float4*)(hs + dst + d);
    float4 pv = *(const float4*)(x2 + src + d);
    float4 r;
    r.x = hv.x + (pv.x - hv.x) * gg;
    r.y = hv.y + (pv.y - hv.y) * gg;
    r.z = hv.z + (pv.z - hv.z) * gg;
    r.w = hv.w + (pv.w - hv.w) * gg;
    *(float4*)(out + dst + d) = r;
  }
}

// ---------------------------------------------------------------------------
extern "C" void kernel_launch(void* const* d_in, const int* in_sizes, int n_in,
                              void* d_out, int out_size, void* d_ws, size_t ws_size,
                              hipStream_t stream) {
  (void)in_sizes; (void)n_in; (void)out_size; (void)ws_size;
  const float* hs    = (const float*)d_in[0];
  const float* orig  = (const float*)d_in[1];
  const float* post  = (const float*)d_in[2];
  const float* prior = (const float*)d_in[3];
  const float* cosb  = (const float*)d_in[4];
  const float* sinb  = (const float*)d_in[5];
  // d_in[6] position_ids: unused by reference
  const float* q_w = (const float*)d_in[7];
  const float* q_b = (const float*)d_in[8];
  const float* k_w = (const float*)d_in[9];
  const float* k_b = (const float*)d_in[10];
  const float* v_w = (const float*)d_in[11];
  const float* v_b = (const float*)d_in[12];
  const float* o_w = (const float*)d_in[13];
  const float* ln1 = (const float*)d_in[14];
  const float* ln2 = (const float*)d_in[15];
  const float* gate_w = (const float*)d_in[16];
  const float* up_w   = (const float*)d_in[17];
  const float* down_w = (const float*)d_in[18];
  const float* beta_ce = (const float*)d_in[19];
  const float* beta_cu = (const float*)d_in[20];
  const float* ce_off  = (const float*)d_in[21];
  float* out = (float*)d_out;

  char* wsp = (char*)d_ws;
  size_t off = 0;
  auto alloc = [&](size_t n) -> char* {
    char* r = wsp + off; off += (n + 255) & ~(size_t)255; return r;
  };
  const size_t SD4 = (size_t)S_TOT * D_DIM * 4;   // 16 MB
  const size_t SI4 = (size_t)S_TOT * I_DIM * 4;   // 44 MB
  const size_t SI2 = (size_t)S_TOT * I_DIM * 2;   // 22 MB

  float* scores  = (float*)alloc((size_t)B_DIM * T_LEN * 4);
  int*   rnk     = (int*)  alloc((size_t)B_DIM * T_LEN * 4);
  int*   tidx    = (int*)  alloc((size_t)S_TOT * 4);
  float* gatebuf = (float*)alloc((size_t)S_TOT * 4);
  u16* qwt = (u16*)alloc((size_t)2048 * 2048 * 2);
  u16* kwt = (u16*)alloc((size_t)2048 * 2048 * 2);
  u16* vwt = (u16*)alloc((size_t)2048 * 2048 * 2);
  u16* owt = (u16*)alloc((size_t)2048 * 2048 * 2);
  u16* gwt = (u16*)alloc((size_t)I_DIM * 2048 * 2);
  u16* uwt = (u16*)alloc((size_t)I_DIM * 2048 * 2);
  u16* dwt = (u16*)alloc((size_t)2048 * I_DIM * 2);
  // region: selh (steps gather..O-proj) then h2 (rmsnorm2..gate/up GEMMs)
  char* r_selh = alloc(SD4);
  float* selh = (float*)r_selh;
  u16*   h2   = (u16*)r_selh;
  // region: h1 (gather..QKV) then o_attn (attn..O-proj) then mlp_in (silu..down)
  char* r_h1 = alloc(SI2);
  u16* h1     = (u16*)r_h1;
  u16* o_attn = (u16*)r_h1;
  u16* mlp_in = (u16*)r_h1;
  // region: q_lin (QKV..attn) then x2 (down..scatter)
  char* r_q = alloc(SD4);
  float* q_lin = (float*)r_q;
  float* x2    = (float*)r_q;
  // region: k_lin (QKV..attn) then gate_lin (gate GEMM..silu)
  char* r_k = alloc(SI4);
  float* k_lin    = (float*)r_k;
  float* gate_lin = (float*)r_k;
  // region: v_lin (QKV..attn) then up_lin (up GEMM..silu)
  char* r_v = alloc(SI4);
  float* v_lin  = (float*)r_v;
  float* up_lin = (float*)r_v;
  float* x1 = (float*)alloc(SD4);

  // 0) output starts as a copy of hidden_states
  hipMemcpyAsync(out, hs, (size_t)B_DIM * T_LEN * D_DIM * 4,
                 hipMemcpyDeviceToDevice, stream);

  // 1) router scores
  router_kernel<<<dim3(B_DIM * T_LEN), 256, 0, stream>>>(orig, post, prior,
                                                         beta_ce, beta_cu, ce_off, scores);
  // 2) top-k selection, temporal order
  rank_kernel<<<dim3(8, B_DIM), 256, 0, stream>>>(scores, rnk);
  compact_kernel<<<dim3(B_DIM), 256, 0, stream>>>(scores, rnk, tidx, gatebuf);

  // 3) weight conversions (transpose to [N][K] bf16)
  transpose_bf16_kernel<<<dim3(64, 64), 256, 0, stream>>>(q_w, qwt, 2048, 2048);
  transpose_bf16_kernel<<<dim3(64, 64), 256, 0, stream>>>(k_w, kwt, 2048, 2048);
  transpose_bf16_kernel<<<dim3(64, 64), 256, 0, stream>>>(v_w, vwt, 2048, 2048);
  transpose_bf16_kernel<<<dim3(64, 64), 256, 0, stream>>>(o_w, owt, 2048, 2048);
  transpose_bf16_kernel<<<dim3(176, 64), 256, 0, stream>>>(gate_w, gwt, 2048, I_DIM);
  transpose_bf16_kernel<<<dim3(176, 64), 256, 0, stream>>>(up_w, uwt, 2048, I_DIM);
  transpose_bf16_kernel<<<dim3(64, 176), 256, 0, stream>>>(down_w, dwt, I_DIM, 2048);

  // 4) gather + rmsnorm1 -> selh (f32), h1 (bf16)
  rmsnorm_kernel<<<dim3(S_TOT), 256, 0, stream>>>(hs, tidx, ln1, selh, h1);

  // 5) QKV GEMMs
  gemm_bf16_kernel<<<dim3(16, 16), 256, 0, stream>>>(h1, qwt, q_lin, q_b, nullptr, 2048, 2048, 2048);
  gemm_bf16_kernel<<<dim3(16, 16), 256, 0, stream>>>(h1, kwt, k_lin, k_b, nullptr, 2048, 2048, 2048);
  gemm_bf16_kernel<<<dim3(16, 16), 256, 0, stream>>>(h1, vwt, v_lin, v_b, nullptr, 2048, 2048, 2048);

  // 6) RoPE in place on q_lin, k_lin
  rope_kernel<<<dim3((S_TOT * H_NUM * 64) / 256), 256, 0, stream>>>(q_lin, k_lin, cosb, sinb, tidx);

  // 7) attention -> o_attn (bf16)
  attn_kernel<<<dim3(S_TOT / 64, H_NUM), 256, 0, stream>>>(q_lin, k_lin, v_lin, o_attn);

  // 8) O-proj + residual -> x1
  gemm_bf16_kernel<<<dim3(16, 16), 256, 0, stream>>>(o_attn, owt, x1, nullptr, selh, 2048, 2048, 2048);

  // 9) rmsnorm2 -> h2 (bf16)
  rmsnorm_kernel<<<dim3(S_TOT), 256, 0, stream>>>(x1, nullptr, ln2, nullptr, h2);

  // 10) gate/up GEMMs
  gemm_bf16_kernel<<<dim3(44, 16), 256, 0, stream>>>(h2, gwt, gate_lin, nullptr, nullptr, 2048, I_DIM, 2048);
  gemm_bf16_kernel<<<dim3(44, 16), 256, 0, stream>>>(h2, uwt, up_lin, nullptr, nullptr, 2048, I_DIM, 2048);

  // 11) silu * up -> mlp_in (bf16)
  silu_mul_kernel<<<dim3(((size_t)S_TOT * I_DIM) / 1024), 256, 0, stream>>>(gate_lin, up_lin, mlp_in);

  // 12) down GEMM + residual -> x2
  gemm_bf16_kernel<<<dim3(16, 16), 256, 0, stream>>>(mlp_in, dwt, x2, nullptr, x1, 2048, 2048, I_DIM);

  // 13) gated scatter into out
  scatter_kernel<<<dim3(S_TOT), 256, 0, stream>>>(hs, x2, tidx, gatebuf, out);
}

// Round 2
// 1087.580 us; speedup vs baseline: 1.5964x; 1.5964x over previous
//
#include <hip/hip_runtime.h>

// ---------------------------------------------------------------------------
// DTFDynamicLayer: router top-k gather -> Qwen2 block (bf16 MFMA GEMMs,
// MFMA flash attention) -> gated scatter.  B=2,T=2048,D=2048,H=16,HD=128,
// I=5632, K=1024, S=2048.  All fixed at compile time.
// ---------------------------------------------------------------------------

typedef unsigned short u16;
typedef unsigned int u32;
typedef short bf16x8 __attribute__((ext_vector_type(8)));
typedef float f32x4 __attribute__((ext_vector_type(4)));

#define T_LEN 2048
#define D_DIM 2048
#define B_DIM 2
#define H_NUM 16
#define HD_DIM 128
#define I_DIM 5632
#define K_CAP 1024
#define S_TOT 2048
#define QKV_N 6144
#define GU_N 11264

__device__ __forceinline__ u16 f2bf(float f) {
  union { float f; u32 u; } a; a.f = f;
  u32 r = a.u + 0x7fffu + ((a.u >> 16) & 1u);
  return (u16)(r >> 16);
}
__device__ __forceinline__ float bf2f(u16 x) {
  return __uint_as_float((u32)x << 16);
}

__device__ __forceinline__ void gld_lds16(const void* g, void* l) {
  void* gg = const_cast<void*>(g);
  __builtin_amdgcn_global_load_lds(
      (__attribute__((address_space(1))) u32*)gg,
      (__attribute__((address_space(3))) u32*)l, 16, 0, 0);
}

// ---------------- router: scores[b,t] = bcu*||o-p|| + bce*(||p-pr||+off) ----
__global__ __launch_bounds__(256)
void router_kernel(const float* __restrict__ orig, const float* __restrict__ post,
                   const float* __restrict__ prior, const float* __restrict__ bce,
                   const float* __restrict__ bcu, const float* __restrict__ coff,
                   float* __restrict__ scores) {
  const int row = blockIdx.x;
  const size_t base = (size_t)row * D_DIM;
  float s1 = 0.f, s2 = 0.f;
  for (int d = threadIdx.x * 4; d < D_DIM; d += 1024) {
    float4 o = *(const float4*)(orig + base + d);
    float4 p = *(const float4*)(post + base + d);
    float4 r = *(const float4*)(prior + base + d);
    float a;
    a = o.x - p.x; s1 += a * a;  a = o.y - p.y; s1 += a * a;
    a = o.z - p.z; s1 += a * a;  a = o.w - p.w; s1 += a * a;
    a = p.x - r.x; s2 += a * a;  a = p.y - r.y; s2 += a * a;
    a = p.z - r.z; s2 += a * a;  a = p.w - r.w; s2 += a * a;
  }
#pragma unroll
  for (int k = 32; k; k >>= 1) { s1 += __shfl_down(s1, k); s2 += __shfl_down(s2, k); }
  __shared__ float r1[4], r2[4];
  const int wv = threadIdx.x >> 6;
  if ((threadIdx.x & 63) == 0) { r1[wv] = s1; r2[wv] = s2; }
  __syncthreads();
  if (threadIdx.x == 0) {
    float cu = sqrtf(r1[0] + r1[1] + r1[2] + r1[3]);
    float ce = sqrtf(r2[0] + r2[1] + r2[2] + r2[3]);
    scores[row] = bcu[0] * cu + bce[0] * (ce + coff[0]);
  }
}

// ---------------- rank: stable top-k rank (matches lax.top_k tie-break) -----
__global__ __launch_bounds__(256)
void rank_kernel(const float* __restrict__ scores, int* __restrict__ rnk) {
  const int b = blockIdx.y;
  const int t = blockIdx.x * 256 + threadIdx.x;
  __shared__ float s[T_LEN];
  for (int u = threadIdx.x; u < T_LEN; u += 256) s[u] = scores[b * T_LEN + u];
  __syncthreads();
  const float st = s[t];
  int r = 0;
  for (int u = 0; u < T_LEN; ++u) {
    float su = s[u];
    r += ((su > st) || (su == st && u < t)) ? 1 : 0;
  }
  rnk[b * T_LEN + t] = r;
}

// ---------------- compact: selected (rank<K) in temporal order --------------
__global__ __launch_bounds__(256)
void compact_kernel(const float* __restrict__ scores, const int* __restrict__ rnk,
                    int* __restrict__ tidx, float* __restrict__ gate) {
  const int b = blockIdx.x;
  const int base = b * T_LEN;
  __shared__ int csum[256];
  int f[8]; int loc = 0;
  const int t0 = threadIdx.x * 8;
#pragma unroll
  for (int i = 0; i < 8; ++i) { f[i] = (rnk[base + t0 + i] < K_CAP) ? 1 : 0; loc += f[i]; }
  csum[threadIdx.x] = loc;
  __syncthreads();
  if (threadIdx.x == 0) {
    int run = 0;
    for (int i = 0; i < 256; ++i) { int tmp = csum[i]; csum[i] = run; run += tmp; }
  }
  __syncthreads();
  int pos = csum[threadIdx.x];
#pragma unroll
  for (int i = 0; i < 8; ++i) {
    if (f[i]) {
      float sc = scores[base + t0 + i];
      tidx[b * K_CAP + pos] = t0 + i;
      gate[b * K_CAP + pos] = 1.f / (1.f + __expf(-sc));
      ++pos;
    }
  }
}

// ---------------- weight transpose + bf16 convert: Wt[n][k] = W[k][n] -------
__global__ __launch_bounds__(256)
void transpose_bf16_kernel(const float* __restrict__ W, u16* __restrict__ Wt,
                           int K, int N) {
  __shared__ float tile[32][33];
  const int bn = blockIdx.x * 32, bk = blockIdx.y * 32;
  const int tx = threadIdx.x & 31, ty = threadIdx.x >> 5;
#pragma unroll
  for (int i = 0; i < 32; i += 8)
    tile[ty + i][tx] = W[(size_t)(bk + ty + i) * N + bn + tx];
  __syncthreads();
#pragma unroll
  for (int i = 0; i < 32; i += 8)
    Wt[(size_t)(bn + ty + i) * K + bk + tx] = f2bf(tile[tx][ty + i]);
}

// ---------------- rmsnorm (optional gather, optional f32 copy, bf16 out) ----
__global__ __launch_bounds__(256)
void rmsnorm_kernel(const float* __restrict__ X, const int* __restrict__ tidx,
                    const float* __restrict__ w, float* __restrict__ xcopy,
                    u16* __restrict__ Y) {
  const int s = blockIdx.x;
  const float* row;
  if (tidx) {
    const int b = s >> 10;
    const int t = tidx[s];
    row = X + ((size_t)b * T_LEN + t) * D_DIM;
  } else {
    row = X + (size_t)s * D_DIM;
  }
  const int d0 = threadIdx.x * 4;
  float4 v0 = *(const float4*)(row + d0);
  float4 v1 = *(const float4*)(row + d0 + 1024);
  float ss = v0.x*v0.x + v0.y*v0.y + v0.z*v0.z + v0.w*v0.w
           + v1.x*v1.x + v1.y*v1.y + v1.z*v1.z + v1.w*v1.w;
#pragma unroll
  for (int k = 32; k; k >>= 1) ss += __shfl_down(ss, k);
  __shared__ float red[4];
  if ((threadIdx.x & 63) == 0) red[threadIdx.x >> 6] = ss;
  __syncthreads();
  const float tot = red[0] + red[1] + red[2] + red[3];
  const float rms = rsqrtf(tot * (1.0f / D_DIM) + 1e-6f);
  if (xcopy) {
    *(float4*)(xcopy + (size_t)s * D_DIM + d0) = v0;
    *(float4*)(xcopy + (size_t)s * D_DIM + d0 + 1024) = v1;
  }
  const float4 w0 = *(const float4*)(w + d0);
  const float4 w1 = *(const float4*)(w + d0 + 1024);
  u16* yp = Y + (size_t)s * D_DIM;
  u32 a0 = (u32)f2bf(v0.x * rms * w0.x) | ((u32)f2bf(v0.y * rms * w0.y) << 16);
  u32 a1 = (u32)f2bf(v0.z * rms * w0.z) | ((u32)f2bf(v0.w * rms * w0.w) << 16);
  *(uint2*)(yp + d0) = make_uint2(a0, a1);
  u32 b0 = (u32)f2bf(v1.x * rms * w1.x) | ((u32)f2bf(v1.y * rms * w1.y) << 16);
  u32 b1 = (u32)f2bf(v1.z * rms * w1.z) | ((u32)f2bf(v1.w * rms * w1.w) << 16);
  *(uint2*)(yp + d0 + 1024) = make_uint2(b0, b1);
}

// ---------------- bf16 MFMA GEMM, m97 structure -----------------------------
// C = A[M,K](bf16) x Bt[N,K](bf16)^T (+bias[col]) (+resid[M,N])
// output: fp32 C  OR bf16 Cbf (exactly one non-null).
__global__ __launch_bounds__(256)
void gemm_bf16_kernel(const u16* __restrict__ A, const u16* __restrict__ Bt,
                      float* __restrict__ C, u16* __restrict__ Cbf,
                      const float* __restrict__ bias,
                      const float* __restrict__ resid, int N, int K) {
  __shared__ u16 As[128 * 32];
  __shared__ u16 Bs[128 * 32];
  const int tid = threadIdx.x;
  const int w = tid >> 6, l = tid & 63;
  const int row0 = blockIdx.y * 128, col0 = blockIdx.x * 128;
  const int wr = (w >> 1) * 64, wc = (w & 1) * 64;
  const int am = l & 15, ak = (l >> 4) * 8;
  const int srow = l >> 2, scol = (l & 3) * 8;

  f32x4 acc[4][4] = {};

  const u16* Abase = A + (size_t)(row0 + srow) * K + scol;
  const u16* Bbase = Bt + (size_t)(col0 + srow) * K + scol;
  const int R0 = (w * 2) * 16, R1 = (w * 2 + 1) * 16;

  for (int k0 = 0; k0 < K; k0 += 32) {
    gld_lds16(Abase + (size_t)R0 * K + k0, &As[R0 * 32]);
    gld_lds16(Abase + (size_t)R1 * K + k0, &As[R1 * 32]);
    gld_lds16(Bbase + (size_t)R0 * K + k0, &Bs[R0 * 32]);
    gld_lds16(Bbase + (size_t)R1 * K + k0, &Bs[R1 * 32]);
    __syncthreads();
    bf16x8 af[4], bfr[4];
#pragma unroll
    for (int i = 0; i < 4; ++i) af[i] = *(const bf16x8*)&As[(wr + i * 16 + am) * 32 + ak];
#pragma unroll
    for (int j = 0; j < 4; ++j) bfr[j] = *(const bf16x8*)&Bs[(wc + j * 16 + am) * 32 + ak];
#pragma unroll
    for (int i = 0; i < 4; ++i)
#pragma unroll
      for (int j = 0; j < 4; ++j)
        acc[i][j] = __builtin_amdgcn_mfma_f32_16x16x32_bf16(af[i], bfr[j], acc[i][j], 0, 0, 0);
    __syncthreads();
  }

  const int rb = wr + (l >> 4) * 4;
  const int cb = wc + (l & 15);
#pragma unroll
  for (int i = 0; i < 4; ++i) {
#pragma unroll
    for (int j = 0; j < 4; ++j) {
      const int colg = col0 + cb + j * 16;
      const float bv = bias ? bias[colg] : 0.0f;
#pragma unroll
      for (int r = 0; r < 4; ++r) {
        const int rowg = row0 + rb + i * 16 + r;
        const size_t idx = (size_t)rowg * N + colg;
        float v = acc[i][j][r] + bv;
        if (resid) v += resid[idx];
        if (Cbf) Cbf[idx] = f2bf(v);
        else C[idx] = v;
      }
    }
  }
}

// ---------------- RoPE in place on bf16 qkv buffer [S, 6144] ----------------
__global__ __launch_bounds__(256)
void rope_kernel(u16* __restrict__ qkv, const float* __restrict__ cosb,
                 const float* __restrict__ sinb, const int* __restrict__ tidx) {
  const int idx = blockIdx.x * 256 + threadIdx.x;  // < S*H*64
  const int d = idx & 63;
  const int h = (idx >> 6) & 15;
  const int s = idx >> 10;
  const int b = s >> 10;
  const int t = tidx[s];
  const size_t base = (size_t)s * QKV_N + h * 128 + d;
  const size_t cb = ((size_t)b * T_LEN + t) * HD_DIM + d;
  const float c1 = cosb[cb], sn1 = sinb[cb];
  const float c2 = cosb[cb + 64], sn2 = sinb[cb + 64];
  float x1v, x2v;
  x1v = bf2f(qkv[base]); x2v = bf2f(qkv[base + 64]);
  qkv[base] = f2bf(x1v * c1 - x2v * sn1);
  qkv[base + 64] = f2bf(x2v * c2 + x1v * sn2);
  x1v = bf2f(qkv[base + 2048]); x2v = bf2f(qkv[base + 2048 + 64]);
  qkv[base + 2048] = f2bf(x1v * c1 - x2v * sn1);
  qkv[base + 2048 + 64] = f2bf(x2v * c2 + x1v * sn2);
}

// ---------------- MFMA flash attention --------------------------------------
// grid (32, H); block 256 (4 waves).  qt = 31 - blockIdx.x (LPT order).
// Each wave: 16 q-rows.  Q frags in regs; K tile in Ks; V^T in Vt; P via Ps.
__global__ __launch_bounds__(256)
void attn_mfma_kernel(const u16* __restrict__ QKV, u16* __restrict__ Og) {
  const int h = blockIdx.y;
  const int qt = 31 - (int)blockIdx.x;
  const int q0 = qt * 64;
  const int tid = threadIdx.x;
  const int w = tid >> 6, l = tid & 63;
  const int lm = l & 15, lk = l >> 4;

  __shared__ u16 Ks[64 * 136];   // K tile [kv][d], padded
  __shared__ u16 Vt[128 * 72];   // V^T tile [d][kv], padded
  __shared__ u16 Ps[64 * 72];    // P tile [q][kv], padded

  const u16* Qg = QKV + h * 128;
  const u16* Kg = QKV + 2048 + h * 128;
  const u16* Vg = QKV + 4096 + h * 128;

  // Q fragments: rows q0 + w*16 + lm, k-chunks of 32 over d=128
  bf16x8 qf[4];
  {
    const u16* qrow = Qg + (size_t)(q0 + w * 16 + lm) * QKV_N;
#pragma unroll
    for (int ks = 0; ks < 4; ++ks)
      qf[ks] = *(const bf16x8*)&qrow[ks * 32 + lk * 8];
  }

  f32x4 oacc[8];
#pragma unroll
  for (int n = 0; n < 8; ++n) oacc[n] = (f32x4){0.f, 0.f, 0.f, 0.f};
  float m_run[4] = {-1e30f, -1e30f, -1e30f, -1e30f};
  float l_run[4] = {0.f, 0.f, 0.f, 0.f};

  for (int kt = 0; kt <= qt; ++kt) {
    const int kv0 = kt * 64;
    __syncthreads();  // previous tile fully consumed
    // stage K: 64 rows x 128 d bf16 -> Ks (b128 copies)
#pragma unroll
    for (int p = 0; p < 4; ++p) {
      const int i = p * 256 + tid;           // 0..1023 chunk of 8 u16
      const int r = i >> 4, c8 = i & 15;
      *(uint4*)&Ks[r * 136 + c8 * 8] =
          *(const uint4*)(Kg + (size_t)(kv0 + r) * QKV_N + c8 * 8);
    }
    // stage V transposed: thread -> one d column, 32 kv values
    {
      const int d = tid >> 1;
      const int kvb = (tid & 1) * 32;
      const u16* vc = Vg + (size_t)(kv0 + kvb) * QKV_N + d;
      u16 vv[32];
#pragma unroll
      for (int j = 0; j < 32; ++j) vv[j] = vc[(size_t)j * QKV_N];
#pragma unroll
      for (int jj = 0; jj < 8; ++jj) {
        u32 lo = (u32)vv[jj * 4] | ((u32)vv[jj * 4 + 1] << 16);
        u32 hi = (u32)vv[jj * 4 + 2] | ((u32)vv[jj * 4 + 3] << 16);
        *(uint2*)&Vt[d * 72 + kvb + jj * 4] = make_uint2(lo, hi);
      }
    }
    __syncthreads();

    // QK^T: S[16q x 64kv] per wave
    f32x4 sacc[4];
#pragma unroll
    for (int j = 0; j < 4; ++j) sacc[j] = (f32x4){0.f, 0.f, 0.f, 0.f};
#pragma unroll
    for (int j = 0; j < 4; ++j)
#pragma unroll
      for (int ks = 0; ks < 4; ++ks) {
        const bf16x8 kf = *(const bf16x8*)&Ks[(j * 16 + lm) * 136 + ks * 32 + lk * 8];
        sacc[j] = __builtin_amdgcn_mfma_f32_16x16x32_bf16(qf[ks], kf, sacc[j], 0, 0, 0);
      }

    // mask + online softmax (in registers, per 16-lane group)
    const float scale = 0.08838834764831845f;  // 1/sqrt(128)
    float mx[4] = {-1e30f, -1e30f, -1e30f, -1e30f};
#pragma unroll
    for (int j = 0; j < 4; ++j) {
      const int colg = kv0 + j * 16 + lm;
#pragma unroll
      for (int r = 0; r < 4; ++r) {
        const int rowg = q0 + w * 16 + lk * 4 + r;
        float s = sacc[j][r] * scale;
        s = (colg > rowg) ? -1e30f : s;
        sacc[j][r] = s;
        mx[r] = fmaxf(mx[r], s);
      }
    }
#pragma unroll
    for (int r = 0; r < 4; ++r)
#pragma unroll
      for (int dlt = 1; dlt < 16; dlt <<= 1)
        mx[r] = fmaxf(mx[r], __shfl_xor(mx[r], dlt));
    float alpha[4];
#pragma unroll
    for (int r = 0; r < 4; ++r) {
      const float mnew = fmaxf(m_run[r], mx[r]);
      const float al = __expf(m_run[r] - mnew);
      float sum = 0.f;
#pragma unroll
      for (int j = 0; j < 4; ++j) {
        const float pe = __expf(sacc[j][r] - mnew);
        sacc[j][r] = pe;
        sum += pe;
      }
#pragma unroll
      for (int dlt = 1; dlt < 16; dlt <<= 1) sum += __shfl_xor(sum, dlt);
      l_run[r] = l_run[r] * al + sum;
      m_run[r] = mnew;
      alpha[r] = al;
    }
#pragma unroll
    for (int n = 0; n < 8; ++n)
#pragma unroll
      for (int r = 0; r < 4; ++r) oacc[n][r] *= alpha[r];

    // P (C-layout) -> Ps (A-layout source); wave-local rows, no barrier needed
#pragma unroll
    for (int j = 0; j < 4; ++j)
#pragma unroll
      for (int r = 0; r < 4; ++r)
        Ps[(w * 16 + lk * 4 + r) * 72 + j * 16 + lm] = f2bf(sacc[j][r]);

    // PV: O[16q x 128d] += P[16 x 64] * V[64 x 128]
#pragma unroll
    for (int ks2 = 0; ks2 < 2; ++ks2) {
      const bf16x8 pf = *(const bf16x8*)&Ps[(w * 16 + lm) * 72 + ks2 * 32 + lk * 8];
#pragma unroll
      for (int n = 0; n < 8; ++n) {
        const bf16x8 vf = *(const bf16x8*)&Vt[(n * 16 + lm) * 72 + ks2 * 32 + lk * 8];
        oacc[n] = __builtin_amdgcn_mfma_f32_16x16x32_bf16(pf, vf, oacc[n], 0, 0, 0);
      }
    }
  }

  // epilogue: O /= l
  float linv[4];
#pragma unroll
  for (int r = 0; r < 4; ++r) linv[r] = 1.f / l_run[r];
#pragma unroll
  for (int n = 0; n < 8; ++n)
#pragma unroll
    for (int r = 0; r < 4; ++r) {
      const int row = q0 + w * 16 + lk * 4 + r;
      Og[(size_t)row * 2048 + h * 128 + n * 16 + lm] = f2bf(oacc[n][r] * linv[r]);
    }
}

// ---------------- silu(gate)*up on fused bf16 gu buffer ---------------------
__global__ __launch_bounds__(256)
void silu_mul_kernel(const u16* __restrict__ gu, u16* __restrict__ out) {
  const size_t i = (size_t)blockIdx.x * 256 + threadIdx.x;  // 4-elem units
  const int s = (int)(i / 1408);
  const int c = (int)(i - (size_t)s * 1408);
  const uint2 g4 = *(const uint2*)&gu[(size_t)s * GU_N + c * 4];
  const uint2 u4 = *(const uint2*)&gu[(size_t)s * GU_N + I_DIM + c * 4];
  float g[4], u[4];
  g[0] = __uint_as_float(g4.x << 16); g[1] = __uint_as_float(g4.x & 0xffff0000u);
  g[2] = __uint_as_float(g4.y << 16); g[3] = __uint_as_float(g4.y & 0xffff0000u);
  u[0] = __uint_as_float(u4.x << 16); u[1] = __uint_as_float(u4.x & 0xffff0000u);
  u[2] = __uint_as_float(u4.y << 16); u[3] = __uint_as_float(u4.y & 0xffff0000u);
  u16 r[4];
#pragma unroll
  for (int j = 0; j < 4; ++j) r[j] = f2bf(g[j] * u[j] / (1.f + __expf(-g[j])));
  u32 a0 = (u32)r[0] | ((u32)r[1] << 16);
  u32 a1 = (u32)r[2] | ((u32)r[3] << 16);
  *(uint2*)&out[(size_t)s * I_DIM + c * 4] = make_uint2(a0, a1);
}

// ---------------- gated scatter back ----------------------------------------
__global__ __launch_bounds__(256)
void scatter_kernel(const float* __restrict__ hs, const float* __restrict__ x2,
                    const int* __restrict__ tidx, const float* __restrict__ gate,
                    float* __restrict__ out) {
  const int s = blockIdx.x;
  const int b = s >> 10;
  const int t = tidx[s];
  const float gg = gate[s];
  const size_t src = (size_t)s * D_DIM;
  const size_t dst = ((size_t)b * T_LEN + t) * D_DIM;
  for (int d = threadIdx.x * 4; d < D_DIM; d += 1024) {
    float4 hv = *(const float4*)(hs + dst + d);
    float4 pv = *(const float4*)(x2 + src + d);
    float4 r;
    r.x = hv.x + (pv.x - hv.x) * gg;
    r.y = hv.y + (pv.y - hv.y) * gg;
    r.z = hv.z + (pv.z - hv.z) * gg;
    r.w = hv.w + (pv.w - hv.w) * gg;
    *(float4*)(out + dst + d) = r;
  }
}

// ---------------------------------------------------------------------------
extern "C" void kernel_launch(void* const* d_in, const int* in_sizes, int n_in,
                              void* d_out, int out_size, void* d_ws, size_t ws_size,
                              hipStream_t stream) {
  (void)in_sizes; (void)n_in; (void)out_size; (void)ws_size;
  const float* hs    = (const float*)d_in[0];
  const float* orig  = (const float*)d_in[1];
  const float* post  = (const float*)d_in[2];
  const float* prior = (const float*)d_in[3];
  const float* cosb  = (const float*)d_in[4];
  const float* sinb  = (const float*)d_in[5];
  const float* q_w = (const float*)d_in[7];
  const float* q_b = (const float*)d_in[8];
  const float* k_w = (const float*)d_in[9];
  const float* k_b = (const float*)d_in[10];
  const float* v_w = (const float*)d_in[11];
  const float* v_b = (const float*)d_in[12];
  const float* o_w = (const float*)d_in[13];
  const float* ln1 = (const float*)d_in[14];
  const float* ln2 = (const float*)d_in[15];
  const float* gate_w = (const float*)d_in[16];
  const float* up_w   = (const float*)d_in[17];
  const float* down_w = (const float*)d_in[18];
  const float* beta_ce = (const float*)d_in[19];
  const float* beta_cu = (const float*)d_in[20];
  const float* ce_off  = (const float*)d_in[21];
  float* out = (float*)d_out;

  char* wsp = (char*)d_ws;
  size_t off = 0;
  auto alloc = [&](size_t n) -> char* {
    char* r = wsp + off; off += (n + 255) & ~(size_t)255; return r;
  };
  const size_t SD4 = (size_t)S_TOT * D_DIM * 4;   // 16 MB

  float* scores  = (float*)alloc((size_t)B_DIM * T_LEN * 4);
  int*   rnk     = (int*)  alloc((size_t)B_DIM * T_LEN * 4);
  int*   tidx    = (int*)  alloc((size_t)S_TOT * 4);
  float* gatebuf = (float*)alloc((size_t)S_TOT * 4);
  float* qkvbias = (float*)alloc((size_t)QKV_N * 4);
  u16* qkvwt = (u16*)alloc((size_t)QKV_N * 2048 * 2);       // 25.2 MB
  u16* owt   = (u16*)alloc((size_t)2048 * 2048 * 2);        //  8.4 MB
  u16* guwt  = (u16*)alloc((size_t)GU_N * 2048 * 2);        // 46.1 MB
  u16* dwt   = (u16*)alloc((size_t)2048 * I_DIM * 2);       // 23.1 MB
  // region A: selh (rms1..O-proj) then h2 (rms2..gate/up)
  char* rA = alloc(SD4);
  float* selh = (float*)rA;
  u16*   h2   = (u16*)rA;
  // region B: h1 (rms1..QKV) then o_attn (attn..O-proj) then mlp_in (silu..down)
  char* rB = alloc((size_t)S_TOT * I_DIM * 2);              // 23.1 MB
  u16* h1     = (u16*)rB;
  u16* o_attn = (u16*)rB;
  u16* mlp_in = (u16*)rB;
  // region C: qkv_bf (QKV..attn) then gu_bf (gate/up..silu) then x2 (down..scatter)
  char* rC = alloc((size_t)S_TOT * GU_N * 2);               // 44 MB
  u16* qkv_bf = (u16*)rC;
  u16* gu_bf  = (u16*)rC;
  float* x2   = (float*)rC;
  float* x1 = (float*)alloc(SD4);

  // 0) output starts as a copy of hidden_states; fused qkv bias
  hipMemcpyAsync(out, hs, (size_t)B_DIM * T_LEN * D_DIM * 4,
                 hipMemcpyDeviceToDevice, stream);
  hipMemcpyAsync(qkvbias, q_b, 2048 * 4, hipMemcpyDeviceToDevice, stream);
  hipMemcpyAsync(qkvbias + 2048, k_b, 2048 * 4, hipMemcpyDeviceToDevice, stream);
  hipMemcpyAsync(qkvbias + 4096, v_b, 2048 * 4, hipMemcpyDeviceToDevice, stream);

  // 1) router scores + top-k selection (temporal order)
  router_kernel<<<dim3(B_DIM * T_LEN), 256, 0, stream>>>(orig, post, prior,
                                                         beta_ce, beta_cu, ce_off, scores);
  rank_kernel<<<dim3(8, B_DIM), 256, 0, stream>>>(scores, rnk);
  compact_kernel<<<dim3(B_DIM), 256, 0, stream>>>(scores, rnk, tidx, gatebuf);

  // 2) weight conversions (transpose to [N][K] bf16); fused layouts
  transpose_bf16_kernel<<<dim3(64, 64), 256, 0, stream>>>(q_w, qkvwt, 2048, 2048);
  transpose_bf16_kernel<<<dim3(64, 64), 256, 0, stream>>>(k_w, qkvwt + (size_t)2048 * 2048, 2048, 2048);
  transpose_bf16_kernel<<<dim3(64, 64), 256, 0, stream>>>(v_w, qkvwt + (size_t)4096 * 2048, 2048, 2048);
  transpose_bf16_kernel<<<dim3(64, 64), 256, 0, stream>>>(o_w, owt, 2048, 2048);
  transpose_bf16_kernel<<<dim3(176, 64), 256, 0, stream>>>(gate_w, guwt, 2048, I_DIM);
  transpose_bf16_kernel<<<dim3(176, 64), 256, 0, stream>>>(up_w, guwt + (size_t)I_DIM * 2048, 2048, I_DIM);
  transpose_bf16_kernel<<<dim3(64, 176), 256, 0, stream>>>(down_w, dwt, I_DIM, 2048);

  // 3) gather + rmsnorm1 -> selh (f32), h1 (bf16)
  rmsnorm_kernel<<<dim3(S_TOT), 256, 0, stream>>>(hs, tidx, ln1, selh, h1);

  // 4) fused QKV GEMM -> qkv_bf (bf16, [S][6144])
  gemm_bf16_kernel<<<dim3(48, 16), 256, 0, stream>>>(h1, qkvwt, nullptr, qkv_bf,
                                                     qkvbias, nullptr, QKV_N, 2048);
  // 5) RoPE in place (q & k halves)
  rope_kernel<<<dim3((S_TOT * H_NUM * 64) / 256), 256, 0, stream>>>(qkv_bf, cosb, sinb, tidx);

  // 6) MFMA flash attention -> o_attn (bf16)
  attn_mfma_kernel<<<dim3(32, H_NUM), 256, 0, stream>>>(qkv_bf, o_attn);

  // 7) O-proj + residual -> x1 (f32)
  gemm_bf16_kernel<<<dim3(16, 16), 256, 0, stream>>>(o_attn, owt, x1, nullptr,
                                                     nullptr, selh, 2048, 2048);

  // 8) rmsnorm2 -> h2 (bf16)
  rmsnorm_kernel<<<dim3(S_TOT), 256, 0, stream>>>(x1, nullptr, ln2, nullptr, h2);

  // 9) fused gate/up GEMM -> gu_bf (bf16, [S][11264])
  gemm_bf16_kernel<<<dim3(88, 16), 256, 0, stream>>>(h2, guwt, nullptr, gu_bf,
                                                     nullptr, nullptr, GU_N, 2048);

  // 10) silu * up -> mlp_in (bf16)
  silu_mul_kernel<<<dim3((S_TOT * (I_DIM / 4)) / 256), 256, 0, stream>>>(gu_bf, mlp_in);

  // 11) down GEMM + residual -> x2 (f32)
  gemm_bf16_kernel<<<dim3(16, 16), 256, 0, stream>>>(mlp_in, dwt, x2, nullptr,
                                                     nullptr, x1, 2048, I_DIM);

  // 12) gated scatter into out
  scatter_kernel<<<dim3(S_TOT), 256, 0, stream>>>(hs, x2, tidx, gatebuf, out);
}